// Round 2
// baseline (289.997 us; speedup 1.0000x reference)
//
#include <hip/hip_runtime.h>

// out[b,h,w,d,c] = in[b,h,w,d] * u[d,c],  u = beta^2 / rowsum(beta^2)
// in: [16,160,320,32] fp32 (26,214,400 elems, 104.9 MB)
// out: [.., 32, 2] fp32 (52,428,800 elems, 209.7 MB)
// Traffic floor 314.6 MB -> ~48 us at the 6.5 TB/s the harness fill achieves.
//
// R4: widen to 16B/lane loads (float4) producing 2x float4 stores per
// thread (32B/lane), all non-temporal (pure streaming; the inter-iteration
// 800 MiB poison fill flushes L2/L3 anyway, so write-allocate is overhead).
// Use clang ext_vector_type for the nontemporal builtins (HIP_vector_type
// is a struct and is rejected -- R3 compile failure).
//
// Thread handling input float4 p covers d = 4p..4p+3 (mod 32).
// stride = 4096*256 = 1,048,576 -> 4*stride % 32 == 0 -> u loop-invariant.

typedef float f32x4 __attribute__((ext_vector_type(4)));

__global__ __launch_bounds__(256) void DS2_87582973100612_kernel(
    const f32x4* __restrict__ in4,
    const float* __restrict__ beta,
    f32x4*       __restrict__ out4,
    int n_in4)
{
    const int gid    = blockIdx.x * blockDim.x + threadIdx.x;
    const int stride = gridDim.x * blockDim.x;

    // d rows owned by this thread: d0..d0+3 (d0 multiple of 4, < 32)
    const int d0 = (4 * gid) & 31;

    float u00, u01, u10, u11, u20, u21, u30, u31;
    {
        const float a0 = beta[2 * (d0 + 0)], a1 = beta[2 * (d0 + 0) + 1];
        const float b0 = beta[2 * (d0 + 1)], b1 = beta[2 * (d0 + 1) + 1];
        const float c0 = beta[2 * (d0 + 2)], c1 = beta[2 * (d0 + 2) + 1];
        const float e0 = beta[2 * (d0 + 3)], e1 = beta[2 * (d0 + 3) + 1];
        const float sa0 = a0 * a0, sa1 = a1 * a1;
        const float sb0 = b0 * b0, sb1 = b1 * b1;
        const float sc0 = c0 * c0, sc1 = c1 * c1;
        const float se0 = e0 * e0, se1 = e1 * e1;
        const float ia = 1.0f / (sa0 + sa1);
        const float ib = 1.0f / (sb0 + sb1);
        const float ic = 1.0f / (sc0 + sc1);
        const float ie = 1.0f / (se0 + se1);
        u00 = sa0 * ia; u01 = sa1 * ia;
        u10 = sb0 * ib; u11 = sb1 * ib;
        u20 = sc0 * ic; u21 = sc1 * ic;
        u30 = se0 * ie; u31 = se1 * ie;
    }

    for (int p = gid; p < n_in4; p += stride) {
        const f32x4 x = __builtin_nontemporal_load(&in4[p]);
        f32x4 y0, y1;
        y0.x = x.x * u00; y0.y = x.x * u01;
        y0.z = x.y * u10; y0.w = x.y * u11;
        y1.x = x.z * u20; y1.y = x.z * u21;
        y1.z = x.w * u30; y1.w = x.w * u31;
        __builtin_nontemporal_store(y0, &out4[2 * p + 0]);
        __builtin_nontemporal_store(y1, &out4[2 * p + 1]);
    }
}

extern "C" void kernel_launch(void* const* d_in, const int* in_sizes, int n_in,
                              void* d_out, int out_size, void* d_ws, size_t ws_size,
                              hipStream_t stream) {
    const float* in   = (const float*)d_in[0];
    const float* beta = (const float*)d_in[1];
    float* out        = (float*)d_out;

    const int n_in4 = in_sizes[0] / 4;  // 6,553,600 input float4s

    const int block = 256;
    const int grid  = 4096;             // 1,048,576 threads

    DS2_87582973100612_kernel<<<grid, block, 0, stream>>>(
        (const f32x4*)in, beta, (f32x4*)out, n_in4);
}

// Round 3
// 276.440 us; speedup vs baseline: 1.0490x; 1.0490x over previous
//
#include <hip/hip_runtime.h>

// out[b,h,w,d,c] = in[b,h,w,d] * u[d,c],  u = beta^2 / rowsum(beta^2)
// in: [16,160,320,32] fp32 (104.9 MB), beta: [32,2], out: 2x in (209.7 MB).
// Traffic floor 314.6 MB -> ~48 us at 6.5 TB/s.
//
// R5: back to the R0 output-centric layout (both sides dense per
// instruction): thread o does an 8B float2 load and a 16B float4 store.
// R4's 16B-load variant made EACH store instruction stride-2 across lanes
// (50% line density, 2x store transactions) and regressed 280->290 us;
// stores are 2/3 of traffic, so per-instruction store density dominates.
// New vs R0: non-temporal load/store (streaming kernel, nothing re-read;
// the 800 MiB inter-iteration poison fill flushes caches anyway, so
// L2/L3 write-allocate is pure overhead).

typedef float f32x2 __attribute__((ext_vector_type(2)));
typedef float f32x4 __attribute__((ext_vector_type(4)));

__global__ __launch_bounds__(256) void DS2_87582973100612_kernel(
    const f32x2* __restrict__ in2,
    const float* __restrict__ beta,
    f32x4*       __restrict__ out4,
    int n_out4)
{
    const int gid    = blockIdx.x * blockDim.x + threadIdx.x;
    const int stride = gridDim.x * blockDim.x; // multiple of 16 -> d0 loop-invariant

    // Output float4 o covers (d0, d1=d0+1) with d0 = (2*o) & 31 (even).
    const int d0 = (2 * gid) & 31;
    const int d1 = d0 + 1;

    const float a0 = beta[2 * d0], a1 = beta[2 * d0 + 1];
    const float b0 = beta[2 * d1], b1 = beta[2 * d1 + 1];
    const float sa0 = a0 * a0, sa1 = a1 * a1;
    const float sb0 = b0 * b0, sb1 = b1 * b1;
    const float inva = 1.0f / (sa0 + sa1);
    const float invb = 1.0f / (sb0 + sb1);
    const float u00 = sa0 * inva, u01 = sa1 * inva; // u[d0, 0], u[d0, 1]
    const float u10 = sb0 * invb, u11 = sb1 * invb; // u[d1, 0], u[d1, 1]

    for (int o = gid; o < n_out4; o += stride) {
        const f32x2 x = __builtin_nontemporal_load(&in2[o]);
        f32x4 y;
        y.x = x.x * u00;
        y.y = x.x * u01;
        y.z = x.y * u10;
        y.w = x.y * u11;
        __builtin_nontemporal_store(y, &out4[o]);
    }
}

extern "C" void kernel_launch(void* const* d_in, const int* in_sizes, int n_in,
                              void* d_out, int out_size, void* d_ws, size_t ws_size,
                              hipStream_t stream) {
    const float* in   = (const float*)d_in[0];
    const float* beta = (const float*)d_in[1];
    float* out        = (float*)d_out;

    const int n_out4 = out_size / 4;  // 13,107,200

    const int block = 256;
    const int grid  = 4096;           // 1,048,576 threads; stride mult of 16

    DS2_87582973100612_kernel<<<grid, block, 0, stream>>>(
        (const f32x2*)in, beta, (f32x4*)out, n_out4);
}